// Round 1
// baseline (19092.812 us; speedup 1.0000x reference)
//
#include <hip/hip_runtime.h>

// ---------------- problem constants ----------------
#define Hd   512            // hidden
#define Fd   128            // features
#define Td   512            // seq len
#define Bd   512            // batch
#define TG   64             // gate rows per wg (4 gates x 16 hidden)
#define BG   64             // batches per group
#define NGRP 8              // groups (==XCDs)
#define WPG  32             // wgs per group
#define LDW  648            // padded K-stride of W slice in LDS (bf16 elems): 640+8
#define LDG  68             // padded batch-stride of gate staging (f32 elems)

typedef __bf16 bf16x8 __attribute__((ext_vector_type(8)));
typedef float  f32x4  __attribute__((ext_vector_type(4)));

__device__ __forceinline__ unsigned short f2bf(float x) {
    unsigned u = __float_as_uint(x);
    unsigned r = (u + 0x7fffu + ((u >> 16) & 1u)) >> 16;   // RNE
    return (unsigned short)r;
}
__device__ __forceinline__ float sigm(float x) {
    return 1.0f / (1.0f + __expf(-x));
}
__device__ __forceinline__ float tanh_fast(float x) {
    float xc = fminf(fmaxf(x, -15.f), 15.f);
    float e  = __expf(2.f * xc);
    return (e - 1.f) / (e + 1.f);
}

// Persistent LSTM kernel. Grid MUST be 256 wgs x 256 threads.
// Group g = blockIdx&7 owns batches [g*64, g*64+64); wg r = blockIdx>>3 owns
// hidden units [r*16, r*16+16) (gate rows {j, H+j, 2H+j, 3H+j}).
__global__ __launch_bounds__(256, 1) void lstm_persist(
    const float* __restrict__ X,     const float* __restrict__ W_ih,
    const float* __restrict__ W_hh,  const float* __restrict__ b_ih,
    const float* __restrict__ b_hh,  const float* __restrict__ W_out,
    const float* __restrict__ b_out, float* __restrict__ out,
    unsigned short* __restrict__ hbuf,   // [2][Bd][Hd] bf16 bits (zeroed)
    unsigned int*  __restrict__ bar)     // NGRP counters, 128B apart (zeroed)
{
    extern __shared__ char smem[];
    unsigned short* Wl    = (unsigned short*)smem;                     // TG*LDW bf16
    float*          gsum  = (float*)(smem + TG * LDW * 2);             // TG*LDG f32
    float*          biasl = (float*)(smem + TG * LDW * 2 + TG * LDG * 4); // TG f32
    float*          hpart = biasl + TG;                                // 256 f32

    const int tid = threadIdx.x;
    const int gid = blockIdx.x;
    const int grp = gid & 7;
    const int r   = gid >> 3;
    const int bb  = grp * BG;
    const int jb  = r * 16;

    // ---- stage W slice into LDS as bf16: rows lr = gate*16+jj, cols 0..511 =
    // W_hh[gate*H + jb+jj][k], cols 512..639 = W_ih[...][k-512] ----
    for (int i = tid; i < TG * (Hd / 4); i += 256) {
        int lr = i >> 7, q = (i & 127) << 2;
        int grow = ((lr >> 4) * Hd) + jb + (lr & 15);
        float4 w = *(const float4*)(W_hh + (size_t)grow * Hd + q);
        ushort4 p; p.x = f2bf(w.x); p.y = f2bf(w.y); p.z = f2bf(w.z); p.w = f2bf(w.w);
        *(ushort4*)(Wl + lr * LDW + q) = p;
    }
    for (int i = tid; i < TG * (Fd / 4); i += 256) {
        int lr = i >> 5, q = (i & 31) << 2;
        int grow = ((lr >> 4) * Hd) + jb + (lr & 15);
        float4 w = *(const float4*)(W_ih + (size_t)grow * Fd + q);
        ushort4 p; p.x = f2bf(w.x); p.y = f2bf(w.y); p.z = f2bf(w.z); p.w = f2bf(w.w);
        *(ushort4*)(Wl + lr * LDW + 512 + q) = p;
    }
    if (tid < TG) {
        int grow = ((tid >> 4) * Hd) + jb + (tid & 15);
        biasl[tid] = b_ih[grow] + b_hh[grow];
    }
    __syncthreads();

    // ---- wave/tile constants ----
    const int lane = tid & 63, wid = tid >> 6;
    const int m16  = lane & 15, quad = lane >> 4;
    const int gr0  = (wid & 1) * 32;          // wave's gate-row offset (local)
    const int bt0  = (wid >> 1) * 32;         // wave's batch offset (in group)
    const unsigned short* wl0 = Wl + (gr0 + m16) * LDW + quad * 8;
    const unsigned short* wl1 = wl0 + 16 * LDW;
    const int brow0 = bb + bt0 + m16;         // global batch rows for B frags
    const int brow1 = brow0 + 16;

    // elementwise mapping: thread -> (batch eb, hidden jjb..jjb+3)
    const int eb  = tid & 63;
    const int jjb = (tid >> 6) << 2;
    float wout[4];
#pragma unroll
    for (int u = 0; u < 4; ++u) wout[u] = W_out[jb + jjb + u];
    const float bo = b_out[0];
    float cst[4] = {0.f, 0.f, 0.f, 0.f};

    unsigned int* mybar = bar + grp * 32;     // 128B-separated counters

    for (int t = 0; t < Td; ++t) {
        const unsigned short* hprev = hbuf + (size_t)((t & 1) ^ 1) * (Bd * Hd);
        const unsigned short* hp0 = hprev + (size_t)brow0 * Hd + quad * 8;
        const unsigned short* hp1 = hprev + (size_t)brow1 * Hd + quad * 8;

        f32x4 acc00 = {0.f,0.f,0.f,0.f}, acc01 = {0.f,0.f,0.f,0.f};
        f32x4 acc10 = {0.f,0.f,0.f,0.f}, acc11 = {0.f,0.f,0.f,0.f};

        // ---- K = 0..511 : h part (bf16 from global hbuf) ----
#pragma unroll 4
        for (int ks = 0; ks < 16; ++ks) {
            bf16x8 a0 = *(const bf16x8*)(wl0 + ks * 32);
            bf16x8 a1 = *(const bf16x8*)(wl1 + ks * 32);
            bf16x8 b0 = *(const bf16x8*)(hp0 + ks * 32);
            bf16x8 b1 = *(const bf16x8*)(hp1 + ks * 32);
            acc00 = __builtin_amdgcn_mfma_f32_16x16x32_bf16(a0, b0, acc00, 0, 0, 0);
            acc01 = __builtin_amdgcn_mfma_f32_16x16x32_bf16(a0, b1, acc01, 0, 0, 0);
            acc10 = __builtin_amdgcn_mfma_f32_16x16x32_bf16(a1, b0, acc10, 0, 0, 0);
            acc11 = __builtin_amdgcn_mfma_f32_16x16x32_bf16(a1, b1, acc11, 0, 0, 0);
        }
        // ---- K = 512..639 : x part (fp32 X, cvt to bf16 on the fly) ----
        {
            const float* x0 = X + ((size_t)brow0 * Td + t) * Fd + quad * 8;
            const float* x1 = X + ((size_t)brow1 * Td + t) * Fd + quad * 8;
#pragma unroll
            for (int ks = 0; ks < 4; ++ks) {
                bf16x8 a0 = *(const bf16x8*)(wl0 + 512 + ks * 32);
                bf16x8 a1 = *(const bf16x8*)(wl1 + 512 + ks * 32);
                float4 xa = *(const float4*)(x0 + ks * 32);
                float4 xb = *(const float4*)(x0 + ks * 32 + 4);
                float4 ya = *(const float4*)(x1 + ks * 32);
                float4 yb = *(const float4*)(x1 + ks * 32 + 4);
                bf16x8 b0, b1;
                b0[0]=(__bf16)xa.x; b0[1]=(__bf16)xa.y; b0[2]=(__bf16)xa.z; b0[3]=(__bf16)xa.w;
                b0[4]=(__bf16)xb.x; b0[5]=(__bf16)xb.y; b0[6]=(__bf16)xb.z; b0[7]=(__bf16)xb.w;
                b1[0]=(__bf16)ya.x; b1[1]=(__bf16)ya.y; b1[2]=(__bf16)ya.z; b1[3]=(__bf16)ya.w;
                b1[4]=(__bf16)yb.x; b1[5]=(__bf16)yb.y; b1[6]=(__bf16)yb.z; b1[7]=(__bf16)yb.w;
                acc00 = __builtin_amdgcn_mfma_f32_16x16x32_bf16(a0, b0, acc00, 0, 0, 0);
                acc01 = __builtin_amdgcn_mfma_f32_16x16x32_bf16(a0, b1, acc01, 0, 0, 0);
                acc10 = __builtin_amdgcn_mfma_f32_16x16x32_bf16(a1, b0, acc10, 0, 0, 0);
                acc11 = __builtin_amdgcn_mfma_f32_16x16x32_bf16(a1, b1, acc11, 0, 0, 0);
            }
        }

        // ---- stage gate preacts to LDS (C-layout: row = quad*4+reg, col = lane&15) ----
        {
            const int row = gr0 + (quad << 2);
            const int col = bt0 + m16;
            float* g00 = gsum + row * LDG + col;
            float* g10 = gsum + (row + 16) * LDG + col;
#pragma unroll
            for (int v = 0; v < 4; ++v) {
                g00[v * LDG]      = acc00[v];
                g00[v * LDG + 16] = acc01[v];
                g10[v * LDG]      = acc10[v];
                g10[v * LDG + 16] = acc11[v];
            }
        }
        __syncthreads();

        // ---- elementwise gate math; c in registers; h -> global bf16 ----
        float part = 0.f;
        ushort4 hp4;
        unsigned short hvb[4];
#pragma unroll
        for (int u = 0; u < 4; ++u) {
            int jj = jjb + u;
            float pi = gsum[jj * LDG + eb]        + biasl[jj];
            float pf = gsum[(16 + jj) * LDG + eb] + biasl[16 + jj];
            float pg = gsum[(32 + jj) * LDG + eb] + biasl[32 + jj];
            float po = gsum[(48 + jj) * LDG + eb] + biasl[48 + jj];
            float ii = sigm(pi), ff = sigm(pf);
            float gg = tanh_fast(pg), oo = sigm(po);
            float c  = ff * cst[u] + ii * gg;
            cst[u]   = c;
            float h  = oo * tanh_fast(c);
            hvb[u]   = f2bf(h);
            part    += h * wout[u];
        }
        hp4.x = hvb[0]; hp4.y = hvb[1]; hp4.z = hvb[2]; hp4.w = hvb[3];
        *(ushort4*)(hbuf + (size_t)(t & 1) * (Bd * Hd) + (size_t)(bb + eb) * Hd + jb + jjb) = hp4;

        hpart[tid] = part;
        __syncthreads();
        if (tid < 64) {
            float s = hpart[tid] + hpart[tid + 64] + hpart[tid + 128] + hpart[tid + 192];
            if (r == 0) s += bo;
            atomicAdd(out + (size_t)(bb + tid) * Td + t, s);
        }

        // ---- group barrier: release h stores, arrive, spin-acquire ----
        __threadfence();
        __syncthreads();
        if (tid == 0) {
            __hip_atomic_fetch_add(mybar, 1u, __ATOMIC_RELEASE, __HIP_MEMORY_SCOPE_AGENT);
            unsigned tgt = (unsigned)(t + 1) * WPG;
            while (__hip_atomic_load(mybar, __ATOMIC_ACQUIRE, __HIP_MEMORY_SCOPE_AGENT) < tgt)
                __builtin_amdgcn_s_sleep(2);
        }
        __syncthreads();
    }
}

extern "C" void kernel_launch(void* const* d_in, const int* in_sizes, int n_in,
                              void* d_out, int out_size, void* d_ws, size_t ws_size,
                              hipStream_t stream) {
    const float* X     = (const float*)d_in[0];
    const float* W_ih  = (const float*)d_in[1];
    const float* W_hh  = (const float*)d_in[2];
    const float* b_ih  = (const float*)d_in[3];
    const float* b_hh  = (const float*)d_in[4];
    const float* W_out = (const float*)d_in[5];
    const float* b_out = (const float*)d_in[6];
    float* out = (float*)d_out;

    unsigned short* hbuf = (unsigned short*)d_ws;                 // 2*Bd*Hd bf16 = 1 MiB
    unsigned int*   bar  = (unsigned int*)((char*)d_ws + 2u * Bd * Hd * 2u);

    // zero h double-buffer + barrier counters; zero out (we accumulate atomically)
    hipMemsetAsync(d_ws, 0, 2u * Bd * Hd * 2u + 4096u, stream);
    hipMemsetAsync(d_out, 0, (size_t)out_size * sizeof(float), stream);

    const size_t smem = (size_t)TG * LDW * 2 + (size_t)TG * LDG * 4 + TG * 4 + 256 * 4; // 101,632 B
    // gfx950 allows up to 160 KiB LDS/wg; set attribute defensively (ignore errors)
    (void)hipFuncSetAttribute((const void*)lstm_persist,
                              hipFuncAttributeMaxDynamicSharedMemorySize, (int)smem);

    lstm_persist<<<dim3(256), dim3(256), smem, stream>>>(
        X, W_ih, W_hh, b_ih, b_hh, W_out, b_out, out, hbuf, bar);
}

// Round 2
// 5345.641 us; speedup vs baseline: 3.5717x; 3.5717x over previous
//
#include <hip/hip_runtime.h>

// ---------------- problem constants ----------------
#define Hd   512            // hidden
#define Fd   128            // features
#define Td   512            // seq len
#define Bd   512            // batch
#define TG   64             // gate rows per wg (4 gates x 16 hidden)
#define BG   64             // batches per group
#define WPG  32             // wgs per group
#define LDW  648            // padded K-stride of W slice in LDS (bf16 elems)
#define LDH  520            // padded batch-row stride of h tile in LDS (bf16 elems)
#define LDG  68             // padded batch-stride of gate staging (f32 elems)

typedef __bf16 bf16x8 __attribute__((ext_vector_type(8)));
typedef float  f32x4  __attribute__((ext_vector_type(4)));
typedef unsigned int u32x4 __attribute__((ext_vector_type(4)));
typedef unsigned int u32x2 __attribute__((ext_vector_type(2)));

__device__ __forceinline__ unsigned short f2bf(float x) {
    unsigned u = __float_as_uint(x);
    unsigned r = (u + 0x7fffu + ((u >> 16) & 1u)) >> 16;   // RNE
    return (unsigned short)r;
}
__device__ __forceinline__ float sigm(float x) {
    return 1.0f / (1.0f + __expf(-x));
}
__device__ __forceinline__ float tanh_fast(float x) {
    float xc = fminf(fmaxf(x, -15.f), 15.f);
    float e  = __expf(2.f * xc);
    return (e - 1.f) / (e + 1.f);
}

// Persistent LSTM. 256 wgs x 256 threads (1 wg/CU by LDS; all co-resident).
// Group g = blockIdx&7 owns batches [g*64, g*64+64); wg r = blockIdx>>3 owns
// hidden units [r*16, r*16+16).
// Cross-wg h exchange: sc1 write-through stores + sc1 loads (device coherence
// point = MALL) + one RELEASE atomic per wg per step; RELAXED polling (no
// buffer_inv / no per-poll L2 invalidate — that was round 1's 37 us/step).
__global__ __launch_bounds__(256, 1) void lstm_persist(
    const float* __restrict__ X,     const float* __restrict__ W_ih,
    const float* __restrict__ W_hh,  const float* __restrict__ b_ih,
    const float* __restrict__ b_hh,  const float* __restrict__ W_out,
    const float* __restrict__ b_out, float* __restrict__ out,
    unsigned short* __restrict__ hbuf,   // [2][Bd][Hd] bf16 bits (zeroed)
    unsigned int*  __restrict__ bar)     // 8 counters, 128B apart (zeroed)
{
    extern __shared__ char smem[];
    unsigned short* Wl    = (unsigned short*)smem;                    // 64*648*2 = 82944 B
    unsigned short* htile = (unsigned short*)(smem + TG * LDW * 2);   // 64*520*2 = 66560 B
    float*          gsum  = (float*)(smem + TG * LDW * 2);            // overlays htile (17408 B)
    float*          biasl = (float*)(smem + TG * LDW * 2 + TG * LDH * 2);  // 256 B
    float*          hpart = biasl + TG;                               // 1024 B

    const int tid = threadIdx.x;
    const int gid = blockIdx.x;
    const int grp = gid & 7;
    const int r   = gid >> 3;
    const int bb  = grp * BG;
    const int jb  = r * 16;

    // ---- stage W slice into LDS as bf16 ----
    for (int i = tid; i < TG * (Hd / 4); i += 256) {
        int lr = i >> 7, q = (i & 127) << 2;
        int grow = ((lr >> 4) * Hd) + jb + (lr & 15);
        float4 w = *(const float4*)(W_hh + (size_t)grow * Hd + q);
        ushort4 p; p.x = f2bf(w.x); p.y = f2bf(w.y); p.z = f2bf(w.z); p.w = f2bf(w.w);
        *(ushort4*)(Wl + lr * LDW + q) = p;
    }
    for (int i = tid; i < TG * (Fd / 4); i += 256) {
        int lr = i >> 5, q = (i & 31) << 2;
        int grow = ((lr >> 4) * Hd) + jb + (lr & 15);
        float4 w = *(const float4*)(W_ih + (size_t)grow * Fd + q);
        ushort4 p; p.x = f2bf(w.x); p.y = f2bf(w.y); p.z = f2bf(w.z); p.w = f2bf(w.w);
        *(ushort4*)(Wl + lr * LDW + 512 + q) = p;
    }
    if (tid < TG) {
        int grow = ((tid >> 4) * Hd) + jb + (tid & 15);
        biasl[tid] = b_ih[grow] + b_hh[grow];
    }
    __syncthreads();

    // ---- wave/tile constants ----
    const int lane = tid & 63, wid = tid >> 6;
    const int m16  = lane & 15, quad = lane >> 4;
    const int gr0  = (wid & 1) * 32;          // gate-row offset (local)
    const int bt0  = (wid >> 1) * 32;         // batch offset (in group)
    const unsigned short* wl0 = Wl + (gr0 + m16) * LDW + quad * 8;
    const unsigned short* wl1 = wl0 + 16 * LDW;
    const int brow0 = bb + bt0 + m16;
    const int brow1 = brow0 + 16;
    const unsigned short* hl0 = htile + (bt0 + m16) * LDH + quad * 8;
    const unsigned short* hl1 = hl0 + 16 * LDH;

    // elementwise mapping
    const int eb  = tid & 63;
    const int jjb = (tid >> 6) << 2;
    float wout[4];
#pragma unroll
    for (int u = 0; u < 4; ++u) wout[u] = W_out[jb + jjb + u];
    const float bo = b_out[0];
    float cst[4] = {0.f, 0.f, 0.f, 0.f};

    unsigned int* mybar = bar + grp * 32;

    // h staging geometry: chunk li = i*256+tid; batch=li>>6, kb=li&63
    unsigned short* hw_lds = htile + (size_t)(tid >> 6) * LDH + (tid & 63) * 8;

    for (int t = 0; t < Td; ++t) {
        const unsigned short* hprev = hbuf + (size_t)((t & 1) ^ 1) * (Bd * Hd);

        f32x4 acc00 = {0.f,0.f,0.f,0.f}, acc01 = {0.f,0.f,0.f,0.f};
        f32x4 acc10 = {0.f,0.f,0.f,0.f}, acc11 = {0.f,0.f,0.f,0.f};

        // ---- A: x part (K = 512..639), fp32 X cvt to bf16 on the fly ----
        {
            const float* x0 = X + ((size_t)brow0 * Td + t) * Fd + quad * 8;
            const float* x1 = X + ((size_t)brow1 * Td + t) * Fd + quad * 8;
#pragma unroll
            for (int ks = 0; ks < 4; ++ks) {
                bf16x8 a0 = *(const bf16x8*)(wl0 + 512 + ks * 32);
                bf16x8 a1 = *(const bf16x8*)(wl1 + 512 + ks * 32);
                float4 xa = *(const float4*)(x0 + ks * 32);
                float4 xb = *(const float4*)(x0 + ks * 32 + 4);
                float4 ya = *(const float4*)(x1 + ks * 32);
                float4 yb = *(const float4*)(x1 + ks * 32 + 4);
                bf16x8 b0, b1;
                b0[0]=(__bf16)xa.x; b0[1]=(__bf16)xa.y; b0[2]=(__bf16)xa.z; b0[3]=(__bf16)xa.w;
                b0[4]=(__bf16)xb.x; b0[5]=(__bf16)xb.y; b0[6]=(__bf16)xb.z; b0[7]=(__bf16)xb.w;
                b1[0]=(__bf16)ya.x; b1[1]=(__bf16)ya.y; b1[2]=(__bf16)ya.z; b1[3]=(__bf16)ya.w;
                b1[4]=(__bf16)yb.x; b1[5]=(__bf16)yb.y; b1[6]=(__bf16)yb.z; b1[7]=(__bf16)yb.w;
                acc00 = __builtin_amdgcn_mfma_f32_16x16x32_bf16(a0, b0, acc00, 0, 0, 0);
                acc01 = __builtin_amdgcn_mfma_f32_16x16x32_bf16(a0, b1, acc01, 0, 0, 0);
                acc10 = __builtin_amdgcn_mfma_f32_16x16x32_bf16(a1, b0, acc10, 0, 0, 0);
                acc11 = __builtin_amdgcn_mfma_f32_16x16x32_bf16(a1, b1, acc11, 0, 0, 0);
            }
        }

        // ---- B: load group h tile (64 KB) with sc1 (device-coherent) ----
        // chunk i (i=0..15): global byte offset = i*4096 from per-thread base.
        u32x4 hv0,hv1,hv2,hv3,hv4,hv5,hv6,hv7,hv8,hv9,hv10,hv11,hv12,hv13,hv14,hv15;
        {
            const unsigned short* p0 =
                hprev + (size_t)(bb + (tid >> 6)) * Hd + (tid & 63) * 8;
            const unsigned short* b0p = p0 + 1 * 2048;   // (2j+1)*4096 bytes, j=0..7
            const unsigned short* b1p = p0 + 3 * 2048;
            const unsigned short* b2p = p0 + 5 * 2048;
            const unsigned short* b3p = p0 + 7 * 2048;
            const unsigned short* b4p = p0 + 9 * 2048;
            const unsigned short* b5p = p0 + 11 * 2048;
            const unsigned short* b6p = p0 + 13 * 2048;
            const unsigned short* b7p = p0 + 15 * 2048;
            asm volatile(
                "global_load_dwordx4 %0,  %16, off offset:-4096 sc1\n\t"
                "global_load_dwordx4 %1,  %16, off sc1\n\t"
                "global_load_dwordx4 %2,  %17, off offset:-4096 sc1\n\t"
                "global_load_dwordx4 %3,  %17, off sc1\n\t"
                "global_load_dwordx4 %4,  %18, off offset:-4096 sc1\n\t"
                "global_load_dwordx4 %5,  %18, off sc1\n\t"
                "global_load_dwordx4 %6,  %19, off offset:-4096 sc1\n\t"
                "global_load_dwordx4 %7,  %19, off sc1\n\t"
                "global_load_dwordx4 %8,  %20, off offset:-4096 sc1\n\t"
                "global_load_dwordx4 %9,  %20, off sc1\n\t"
                "global_load_dwordx4 %10, %21, off offset:-4096 sc1\n\t"
                "global_load_dwordx4 %11, %21, off sc1\n\t"
                "global_load_dwordx4 %12, %22, off offset:-4096 sc1\n\t"
                "global_load_dwordx4 %13, %22, off sc1\n\t"
                "global_load_dwordx4 %14, %23, off offset:-4096 sc1\n\t"
                "global_load_dwordx4 %15, %23, off sc1\n\t"
                "s_waitcnt vmcnt(0)"
                : "=&v"(hv0), "=&v"(hv1), "=&v"(hv2), "=&v"(hv3),
                  "=&v"(hv4), "=&v"(hv5), "=&v"(hv6), "=&v"(hv7),
                  "=&v"(hv8), "=&v"(hv9), "=&v"(hv10), "=&v"(hv11),
                  "=&v"(hv12), "=&v"(hv13), "=&v"(hv14), "=&v"(hv15)
                : "v"(b0p), "v"(b1p), "v"(b2p), "v"(b3p),
                  "v"(b4p), "v"(b5p), "v"(b6p), "v"(b7p)
                : "memory");
        }
        // ---- C: stage h tile to LDS (stride +4 batches = +2080 elems per i) ----
        *(u32x4*)(hw_lds + 0 * 2080)  = hv0;  *(u32x4*)(hw_lds + 1 * 2080)  = hv1;
        *(u32x4*)(hw_lds + 2 * 2080)  = hv2;  *(u32x4*)(hw_lds + 3 * 2080)  = hv3;
        *(u32x4*)(hw_lds + 4 * 2080)  = hv4;  *(u32x4*)(hw_lds + 5 * 2080)  = hv5;
        *(u32x4*)(hw_lds + 6 * 2080)  = hv6;  *(u32x4*)(hw_lds + 7 * 2080)  = hv7;
        *(u32x4*)(hw_lds + 8 * 2080)  = hv8;  *(u32x4*)(hw_lds + 9 * 2080)  = hv9;
        *(u32x4*)(hw_lds + 10 * 2080) = hv10; *(u32x4*)(hw_lds + 11 * 2080) = hv11;
        *(u32x4*)(hw_lds + 12 * 2080) = hv12; *(u32x4*)(hw_lds + 13 * 2080) = hv13;
        *(u32x4*)(hw_lds + 14 * 2080) = hv14; *(u32x4*)(hw_lds + 15 * 2080) = hv15;
        __syncthreads();                                   // D

        // ---- E: h part (K = 0..511) from LDS ----
#pragma unroll 4
        for (int ks = 0; ks < 16; ++ks) {
            bf16x8 a0 = *(const bf16x8*)(wl0 + ks * 32);
            bf16x8 a1 = *(const bf16x8*)(wl1 + ks * 32);
            bf16x8 b0 = *(const bf16x8*)(hl0 + ks * 32);
            bf16x8 b1 = *(const bf16x8*)(hl1 + ks * 32);
            acc00 = __builtin_amdgcn_mfma_f32_16x16x32_bf16(a0, b0, acc00, 0, 0, 0);
            acc01 = __builtin_amdgcn_mfma_f32_16x16x32_bf16(a0, b1, acc01, 0, 0, 0);
            acc10 = __builtin_amdgcn_mfma_f32_16x16x32_bf16(a1, b0, acc10, 0, 0, 0);
            acc11 = __builtin_amdgcn_mfma_f32_16x16x32_bf16(a1, b1, acc11, 0, 0, 0);
        }
        __syncthreads();                                   // F: htile free

        // ---- G: gate preacts to LDS (C-layout: row = quad*4+v, col = lane&15) ----
        {
            const int row = gr0 + (quad << 2);
            const int col = bt0 + m16;
            float* g00 = gsum + row * LDG + col;
            float* g10 = gsum + (row + 16) * LDG + col;
#pragma unroll
            for (int v = 0; v < 4; ++v) {
                g00[v * LDG]      = acc00[v];
                g00[v * LDG + 16] = acc01[v];
                g10[v * LDG]      = acc10[v];
                g10[v * LDG + 16] = acc11[v];
            }
        }
        __syncthreads();                                   // H

        // ---- I: gate math; c in regs; h -> global via sc1 write-through ----
        float part = 0.f;
        unsigned short hvb[4];
#pragma unroll
        for (int u = 0; u < 4; ++u) {
            int jj = jjb + u;
            float pi = gsum[jj * LDG + eb]        + biasl[jj];
            float pf = gsum[(16 + jj) * LDG + eb] + biasl[16 + jj];
            float pg = gsum[(32 + jj) * LDG + eb] + biasl[32 + jj];
            float po = gsum[(48 + jj) * LDG + eb] + biasl[48 + jj];
            float ii = sigm(pi), ff = sigm(pf);
            float gg = tanh_fast(pg), oo = sigm(po);
            float c  = ff * cst[u] + ii * gg;
            cst[u]   = c;
            float h  = oo * tanh_fast(c);
            hvb[u]   = f2bf(h);
            part    += h * wout[u];
        }
        {
            u32x2 hd2;
            hd2[0] = (unsigned)hvb[0] | ((unsigned)hvb[1] << 16);
            hd2[1] = (unsigned)hvb[2] | ((unsigned)hvb[3] << 16);
            unsigned short* hwp =
                hbuf + (size_t)(t & 1) * (Bd * Hd) + (size_t)(bb + eb) * Hd + jb + jjb;
            asm volatile("global_store_dwordx2 %0, %1, off sc1"
                         :: "v"(hwp), "v"(hd2) : "memory");
            asm volatile("s_waitcnt vmcnt(0)" ::: "memory");  // J: durable at MALL
        }
        hpart[tid] = part;
        __syncthreads();

        // ---- K: output reduce + group barrier ----
        if (tid < 64) {
            float s = hpart[tid] + hpart[tid + 64] + hpart[tid + 128] + hpart[tid + 192];
            if (r == 0) s += bo;
            atomicAdd(out + (size_t)(bb + tid) * Td + t, s);
        }
        if (tid == 0) {
            __hip_atomic_fetch_add(mybar, 1u, __ATOMIC_RELEASE, __HIP_MEMORY_SCOPE_AGENT);
            unsigned tgt = (unsigned)(t + 1) * WPG;
            while (__hip_atomic_load(mybar, __ATOMIC_RELAXED, __HIP_MEMORY_SCOPE_AGENT) < tgt)
                __builtin_amdgcn_s_sleep(1);
        }
        __syncthreads();                                   // L
    }
}

extern "C" void kernel_launch(void* const* d_in, const int* in_sizes, int n_in,
                              void* d_out, int out_size, void* d_ws, size_t ws_size,
                              hipStream_t stream) {
    const float* X     = (const float*)d_in[0];
    const float* W_ih  = (const float*)d_in[1];
    const float* W_hh  = (const float*)d_in[2];
    const float* b_ih  = (const float*)d_in[3];
    const float* b_hh  = (const float*)d_in[4];
    const float* W_out = (const float*)d_in[5];
    const float* b_out = (const float*)d_in[6];
    float* out = (float*)d_out;

    unsigned short* hbuf = (unsigned short*)d_ws;                 // 2*Bd*Hd bf16 = 1 MiB
    unsigned int*   bar  = (unsigned int*)((char*)d_ws + 2u * Bd * Hd * 2u);

    hipMemsetAsync(d_ws, 0, 2u * Bd * Hd * 2u + 4096u, stream);
    hipMemsetAsync(d_out, 0, (size_t)out_size * sizeof(float), stream);

    const size_t smem = (size_t)TG * LDW * 2      // W slice       82944
                      + (size_t)TG * LDH * 2      // htile/gsum    66560
                      + TG * 4 + 256 * 4;         // bias + hpart   1280  => 150784
    (void)hipFuncSetAttribute((const void*)lstm_persist,
                              hipFuncAttributeMaxDynamicSharedMemorySize, (int)smem);

    lstm_persist<<<dim3(256), dim3(256), smem, stream>>>(
        X, W_ih, W_hh, b_ih, b_hh, W_out, b_out, out, hbuf, bar);
}

// Round 3
// 3685.690 us; speedup vs baseline: 5.1803x; 1.4504x over previous
//
#include <hip/hip_runtime.h>

// ---------------- problem constants ----------------
#define Hd   512            // hidden
#define Fd   128            // features
#define Td   512            // seq len
#define Bd   512            // batch
#define TG   64             // gate rows per wg (4 gates x 16 hidden)
#define BG   64             // batches per group
#define WPG  32             // wgs per group
#define LDW  648            // padded K-stride of W slice in LDS (bf16 elems)
#define LDH  520            // padded batch-row stride of h tile in LDS (bf16 elems)
#define LDG  68             // padded batch-stride of gate staging (f32 elems)

typedef __bf16 bf16x8 __attribute__((ext_vector_type(8)));
typedef float  f32x4  __attribute__((ext_vector_type(4)));
typedef unsigned int u32x4 __attribute__((ext_vector_type(4)));
typedef unsigned int u32x2 __attribute__((ext_vector_type(2)));

__device__ __forceinline__ unsigned short f2bf(float x) {
    unsigned u = __float_as_uint(x);
    unsigned r = (u + 0x7fffu + ((u >> 16) & 1u)) >> 16;   // RNE
    return (unsigned short)r;
}
__device__ __forceinline__ float sigm(float x) {
    return 1.0f / (1.0f + __expf(-x));
}
__device__ __forceinline__ float tanh_fast(float x) {
    float xc = fminf(fmaxf(x, -15.f), 15.f);
    float e  = __expf(2.f * xc);
    return (e - 1.f) / (e + 1.f);
}

// Persistent LSTM. 256 wgs x 256 threads (1 wg/CU by LDS; all co-resident).
// Group g = blockIdx&7 owns batches [g*64, g*64+64); wg r = blockIdx>>3 owns
// hidden units [r*16, r*16+16).
// h exchange: sc1 write-through stores + vmcnt(0) drain (durable at coherence
// point) -> RELAXED flag increment (round 2's RELEASE emitted buffer_wbl2 =
// 32 serialized L2-writeback scans per XCD per step ~= 8 us/step).
// x-projection for step t+1 is computed inside the barrier-skew window.
__global__ __launch_bounds__(256, 1) void lstm_persist(
    const float* __restrict__ X,     const float* __restrict__ W_ih,
    const float* __restrict__ W_hh,  const float* __restrict__ b_ih,
    const float* __restrict__ b_hh,  const float* __restrict__ W_out,
    const float* __restrict__ b_out, float* __restrict__ out,
    unsigned short* __restrict__ hbuf,   // [2][Bd][Hd] bf16 bits (zeroed)
    unsigned int*  __restrict__ bar)     // 8 counters, 128B apart (zeroed)
{
    extern __shared__ char smem[];
    unsigned short* Wl    = (unsigned short*)smem;                    // 64*648*2 = 82944 B
    unsigned short* htile = (unsigned short*)(smem + TG * LDW * 2);   // 64*520*2 = 66560 B
    float*          gsum  = (float*)(smem + TG * LDW * 2);            // overlays htile
    float*          biasl = (float*)(smem + TG * LDW * 2 + TG * LDH * 2);
    float*          hpart = biasl + TG;

    const int tid = threadIdx.x;
    const int gid = blockIdx.x;
    const int grp = gid & 7;
    const int r   = gid >> 3;
    const int bb  = grp * BG;
    const int jb  = r * 16;

    // ---- stage W slice into LDS as bf16 ----
    for (int i = tid; i < TG * (Hd / 4); i += 256) {
        int lr = i >> 7, q = (i & 127) << 2;
        int grow = ((lr >> 4) * Hd) + jb + (lr & 15);
        float4 w = *(const float4*)(W_hh + (size_t)grow * Hd + q);
        ushort4 p; p.x = f2bf(w.x); p.y = f2bf(w.y); p.z = f2bf(w.z); p.w = f2bf(w.w);
        *(ushort4*)(Wl + lr * LDW + q) = p;
    }
    for (int i = tid; i < TG * (Fd / 4); i += 256) {
        int lr = i >> 5, q = (i & 31) << 2;
        int grow = ((lr >> 4) * Hd) + jb + (lr & 15);
        float4 w = *(const float4*)(W_ih + (size_t)grow * Fd + q);
        ushort4 p; p.x = f2bf(w.x); p.y = f2bf(w.y); p.z = f2bf(w.z); p.w = f2bf(w.w);
        *(ushort4*)(Wl + lr * LDW + 512 + q) = p;
    }
    if (tid < TG) {
        int grow = ((tid >> 4) * Hd) + jb + (tid & 15);
        biasl[tid] = b_ih[grow] + b_hh[grow];
    }
    __syncthreads();

    // ---- wave/tile constants ----
    const int lane = tid & 63, wid = tid >> 6;
    const int m16  = lane & 15, quad = lane >> 4;
    const int gr0  = (wid & 1) * 32;          // gate-row offset (local)
    const int bt0  = (wid >> 1) * 32;         // batch offset (in group)
    const unsigned short* wl0 = Wl + (gr0 + m16) * LDW + quad * 8;
    const unsigned short* wl1 = wl0 + 16 * LDW;
    const int brow0 = bb + bt0 + m16;
    const int brow1 = brow0 + 16;
    const unsigned short* hl0 = htile + (bt0 + m16) * LDH + quad * 8;
    const unsigned short* hl1 = hl0 + 16 * LDH;

    // elementwise mapping
    const int eb  = tid & 63;
    const int jjb = (tid >> 6) << 2;
    float wout[4];
#pragma unroll
    for (int u = 0; u < 4; ++u) wout[u] = W_out[jb + jjb + u];
    const float bo = b_out[0];
    float cst[4] = {0.f, 0.f, 0.f, 0.f};

    unsigned int* mybar = bar + grp * 32;
    unsigned short* hw_lds = htile + (size_t)(tid >> 6) * LDH + (tid & 63) * 8;

    f32x4 acc00, acc01, acc10, acc11;
    const float* xp0 = X + (size_t)brow0 * (Td * Fd) + quad * 8;
    const float* xp1 = X + (size_t)brow1 * (Td * Fd) + quad * 8;

    // x-projection MFMAs for one timestep (reads current xp0/xp1)
    auto do_xpart = [&]() {
#pragma unroll
        for (int ks = 0; ks < 4; ++ks) {
            bf16x8 a0 = *(const bf16x8*)(wl0 + 512 + ks * 32);
            bf16x8 a1 = *(const bf16x8*)(wl1 + 512 + ks * 32);
            float4 xa = *(const float4*)(xp0 + ks * 32);
            float4 xb = *(const float4*)(xp0 + ks * 32 + 4);
            float4 ya = *(const float4*)(xp1 + ks * 32);
            float4 yb = *(const float4*)(xp1 + ks * 32 + 4);
            bf16x8 b0, b1;
            b0[0]=(__bf16)xa.x; b0[1]=(__bf16)xa.y; b0[2]=(__bf16)xa.z; b0[3]=(__bf16)xa.w;
            b0[4]=(__bf16)xb.x; b0[5]=(__bf16)xb.y; b0[6]=(__bf16)xb.z; b0[7]=(__bf16)xb.w;
            b1[0]=(__bf16)ya.x; b1[1]=(__bf16)ya.y; b1[2]=(__bf16)ya.z; b1[3]=(__bf16)ya.w;
            b1[4]=(__bf16)yb.x; b1[5]=(__bf16)yb.y; b1[6]=(__bf16)yb.z; b1[7]=(__bf16)yb.w;
            acc00 = __builtin_amdgcn_mfma_f32_16x16x32_bf16(a0, b0, acc00, 0, 0, 0);
            acc01 = __builtin_amdgcn_mfma_f32_16x16x32_bf16(a0, b1, acc01, 0, 0, 0);
            acc10 = __builtin_amdgcn_mfma_f32_16x16x32_bf16(a1, b0, acc10, 0, 0, 0);
            acc11 = __builtin_amdgcn_mfma_f32_16x16x32_bf16(a1, b1, acc11, 0, 0, 0);
        }
    };

    // prologue: x-part for t=0
    acc00 = f32x4{0.f,0.f,0.f,0.f}; acc01 = f32x4{0.f,0.f,0.f,0.f};
    acc10 = f32x4{0.f,0.f,0.f,0.f}; acc11 = f32x4{0.f,0.f,0.f,0.f};
    do_xpart();

    for (int t = 0; t < Td; ++t) {
        // ---- poll: all wgs have stored h(t-1) ----
        if (t > 0 && tid == 0) {
            unsigned tgt = (unsigned)t * WPG;
            while (__hip_atomic_load(mybar, __ATOMIC_RELAXED, __HIP_MEMORY_SCOPE_AGENT) < tgt)
                __builtin_amdgcn_s_sleep(2);
        }
        __syncthreads();                                   // A: flag seen; gsum/hpart free

        const unsigned short* hprev = hbuf + (size_t)((t & 1) ^ 1) * (Bd * Hd);

        // ---- load group h tile (64 KB) with sc1 and stage to LDS ----
        u32x4 hv0,hv1,hv2,hv3,hv4,hv5,hv6,hv7,hv8,hv9,hv10,hv11,hv12,hv13,hv14,hv15;
        {
            const unsigned short* p0 =
                hprev + (size_t)(bb + (tid >> 6)) * Hd + (tid & 63) * 8;
            const unsigned short* b0p = p0 + 1 * 2048;
            const unsigned short* b1p = p0 + 3 * 2048;
            const unsigned short* b2p = p0 + 5 * 2048;
            const unsigned short* b3p = p0 + 7 * 2048;
            const unsigned short* b4p = p0 + 9 * 2048;
            const unsigned short* b5p = p0 + 11 * 2048;
            const unsigned short* b6p = p0 + 13 * 2048;
            const unsigned short* b7p = p0 + 15 * 2048;
            asm volatile(
                "global_load_dwordx4 %0,  %16, off offset:-4096 sc1\n\t"
                "global_load_dwordx4 %1,  %16, off sc1\n\t"
                "global_load_dwordx4 %2,  %17, off offset:-4096 sc1\n\t"
                "global_load_dwordx4 %3,  %17, off sc1\n\t"
                "global_load_dwordx4 %4,  %18, off offset:-4096 sc1\n\t"
                "global_load_dwordx4 %5,  %18, off sc1\n\t"
                "global_load_dwordx4 %6,  %19, off offset:-4096 sc1\n\t"
                "global_load_dwordx4 %7,  %19, off sc1\n\t"
                "global_load_dwordx4 %8,  %20, off offset:-4096 sc1\n\t"
                "global_load_dwordx4 %9,  %20, off sc1\n\t"
                "global_load_dwordx4 %10, %21, off offset:-4096 sc1\n\t"
                "global_load_dwordx4 %11, %21, off sc1\n\t"
                "global_load_dwordx4 %12, %22, off offset:-4096 sc1\n\t"
                "global_load_dwordx4 %13, %22, off sc1\n\t"
                "global_load_dwordx4 %14, %23, off offset:-4096 sc1\n\t"
                "global_load_dwordx4 %15, %23, off sc1\n\t"
                "s_waitcnt vmcnt(0)"
                : "=&v"(hv0), "=&v"(hv1), "=&v"(hv2), "=&v"(hv3),
                  "=&v"(hv4), "=&v"(hv5), "=&v"(hv6), "=&v"(hv7),
                  "=&v"(hv8), "=&v"(hv9), "=&v"(hv10), "=&v"(hv11),
                  "=&v"(hv12), "=&v"(hv13), "=&v"(hv14), "=&v"(hv15)
                : "v"(b0p), "v"(b1p), "v"(b2p), "v"(b3p),
                  "v"(b4p), "v"(b5p), "v"(b6p), "v"(b7p)
                : "memory");
        }
        *(u32x4*)(hw_lds + 0 * 2080)  = hv0;  *(u32x4*)(hw_lds + 1 * 2080)  = hv1;
        *(u32x4*)(hw_lds + 2 * 2080)  = hv2;  *(u32x4*)(hw_lds + 3 * 2080)  = hv3;
        *(u32x4*)(hw_lds + 4 * 2080)  = hv4;  *(u32x4*)(hw_lds + 5 * 2080)  = hv5;
        *(u32x4*)(hw_lds + 6 * 2080)  = hv6;  *(u32x4*)(hw_lds + 7 * 2080)  = hv7;
        *(u32x4*)(hw_lds + 8 * 2080)  = hv8;  *(u32x4*)(hw_lds + 9 * 2080)  = hv9;
        *(u32x4*)(hw_lds + 10 * 2080) = hv10; *(u32x4*)(hw_lds + 11 * 2080) = hv11;
        *(u32x4*)(hw_lds + 12 * 2080) = hv12; *(u32x4*)(hw_lds + 13 * 2080) = hv13;
        *(u32x4*)(hw_lds + 14 * 2080) = hv14; *(u32x4*)(hw_lds + 15 * 2080) = hv15;
        __syncthreads();                                   // B: htile ready

        // ---- h part (K = 0..511) from LDS, on top of x-part accs ----
#pragma unroll 4
        for (int ks = 0; ks < 16; ++ks) {
            bf16x8 a0 = *(const bf16x8*)(wl0 + ks * 32);
            bf16x8 a1 = *(const bf16x8*)(wl1 + ks * 32);
            bf16x8 b0 = *(const bf16x8*)(hl0 + ks * 32);
            bf16x8 b1 = *(const bf16x8*)(hl1 + ks * 32);
            acc00 = __builtin_amdgcn_mfma_f32_16x16x32_bf16(a0, b0, acc00, 0, 0, 0);
            acc01 = __builtin_amdgcn_mfma_f32_16x16x32_bf16(a0, b1, acc01, 0, 0, 0);
            acc10 = __builtin_amdgcn_mfma_f32_16x16x32_bf16(a1, b0, acc10, 0, 0, 0);
            acc11 = __builtin_amdgcn_mfma_f32_16x16x32_bf16(a1, b1, acc11, 0, 0, 0);
        }
        __syncthreads();                                   // C: htile free

        // ---- gate preacts to LDS (C-layout: row = quad*4+v, col = lane&15) ----
        {
            const int row = gr0 + (quad << 2);
            const int col = bt0 + m16;
            float* g00 = gsum + row * LDG + col;
            float* g10 = gsum + (row + 16) * LDG + col;
#pragma unroll
            for (int v = 0; v < 4; ++v) {
                g00[v * LDG]      = acc00[v];
                g00[v * LDG + 16] = acc01[v];
                g10[v * LDG]      = acc10[v];
                g10[v * LDG + 16] = acc11[v];
            }
        }
        __syncthreads();                                   // D: gsum ready

        // ---- gate math; c in regs; h -> global via sc1 write-through ----
        float part = 0.f;
        unsigned short hvb[4];
#pragma unroll
        for (int u = 0; u < 4; ++u) {
            int jj = jjb + u;
            float pi = gsum[jj * LDG + eb]        + biasl[jj];
            float pf = gsum[(16 + jj) * LDG + eb] + biasl[16 + jj];
            float pg = gsum[(32 + jj) * LDG + eb] + biasl[32 + jj];
            float po = gsum[(48 + jj) * LDG + eb] + biasl[48 + jj];
            float ii = sigm(pi), ff = sigm(pf);
            float gg = tanh_fast(pg), oo = sigm(po);
            float c  = ff * cst[u] + ii * gg;
            cst[u]   = c;
            float h  = oo * tanh_fast(c);
            hvb[u]   = f2bf(h);
            part    += h * wout[u];
        }
        {
            u32x2 hd2;
            hd2[0] = (unsigned)hvb[0] | ((unsigned)hvb[1] << 16);
            hd2[1] = (unsigned)hvb[2] | ((unsigned)hvb[3] << 16);
            unsigned short* hwp =
                hbuf + (size_t)(t & 1) * (Bd * Hd) + (size_t)(bb + eb) * Hd + jb + jjb;
            asm volatile("global_store_dwordx2 %0, %1, off sc1"
                         :: "v"(hwp), "v"(hd2) : "memory");
            asm volatile("s_waitcnt vmcnt(0)" ::: "memory");  // durable at coherence point
        }
        // ---- flag: RELAXED (ordering provided by the vmcnt(0) drain above) ----
        if (tid == 0)
            __hip_atomic_fetch_add(mybar, 1u, __ATOMIC_RELAXED, __HIP_MEMORY_SCOPE_AGENT);

        hpart[tid] = part;

        // ---- overlap barrier skew: x-part for t+1 ----
        acc00 = f32x4{0.f,0.f,0.f,0.f}; acc01 = f32x4{0.f,0.f,0.f,0.f};
        acc10 = f32x4{0.f,0.f,0.f,0.f}; acc11 = f32x4{0.f,0.f,0.f,0.f};
        if (t + 1 < Td) {
            xp0 += Fd; xp1 += Fd;
            do_xpart();
        }

        __syncthreads();                                   // E: hpart ready
        if (tid < 64) {
            float s = hpart[tid] + hpart[tid + 64] + hpart[tid + 128] + hpart[tid + 192];
            if (r == 0) s += bo;
            atomicAdd(out + (size_t)(bb + tid) * Td + t, s);
        }
    }
}

extern "C" void kernel_launch(void* const* d_in, const int* in_sizes, int n_in,
                              void* d_out, int out_size, void* d_ws, size_t ws_size,
                              hipStream_t stream) {
    const float* X     = (const float*)d_in[0];
    const float* W_ih  = (const float*)d_in[1];
    const float* W_hh  = (const float*)d_in[2];
    const float* b_ih  = (const float*)d_in[3];
    const float* b_hh  = (const float*)d_in[4];
    const float* W_out = (const float*)d_in[5];
    const float* b_out = (const float*)d_in[6];
    float* out = (float*)d_out;

    unsigned short* hbuf = (unsigned short*)d_ws;                 // 2*Bd*Hd bf16 = 1 MiB
    unsigned int*   bar  = (unsigned int*)((char*)d_ws + 2u * Bd * Hd * 2u);

    hipMemsetAsync(d_ws, 0, 2u * Bd * Hd * 2u + 4096u, stream);
    hipMemsetAsync(d_out, 0, (size_t)out_size * sizeof(float), stream);

    const size_t smem = (size_t)TG * LDW * 2      // W slice       82944
                      + (size_t)TG * LDH * 2      // htile/gsum    66560
                      + TG * 4 + 256 * 4;         // bias + hpart   1280  => 150784
    (void)hipFuncSetAttribute((const void*)lstm_persist,
                              hipFuncAttributeMaxDynamicSharedMemorySize, (int)smem);

    lstm_persist<<<dim3(256), dim3(256), smem, stream>>>(
        X, W_ih, W_hh, b_ih, b_hh, W_out, b_out, out, hbuf, bar);
}